// Round 12
// baseline (1868.219 us; speedup 1.0000x reference)
//
#include <hip/hip_runtime.h>

typedef __attribute__((ext_vector_type(8))) short short8;
typedef __attribute__((ext_vector_type(4))) float f32x4;

// Problem dims
#define BDIM 4096
#define INDIM 1024
#define HDIM 2048
#define KDIM 3072   // IN + H
#define NDIM 8192   // 4*H
#define OUT_HALF 8388608  // 4096*2048
#define NKT 96      // K-tiles of 32
#define ACHUNKS 1572864

__device__ __forceinline__ unsigned short f2bf(float f) {
  unsigned u = __float_as_uint(f);
  u += 0x7FFFu + ((u >> 16) & 1u);
  return (unsigned short)(u >> 16);
}

__device__ __forceinline__ float sigmoidf_(float x) {
  return 1.0f / (1.0f + __expf(-x));
}

// Merged pack: A = [x|h] bf16 [4096][3072]; W' gate-interleaved bf16 [8192][3072];
// bias[n'] = b_ih + b_hh.
__global__ __launch_bounds__(256) void pack_all(
    const float* __restrict__ x, const float* __restrict__ hh,
    const float* __restrict__ w_ih, const float* __restrict__ w_hh,
    const float* __restrict__ b_ih, const float* __restrict__ b_hh,
    unsigned short* __restrict__ A, unsigned short* __restrict__ W,
    float* __restrict__ bias) {
  int idx = blockIdx.x * 256 + threadIdx.x;
  if (idx < ACHUNKS) {
    int m = idx / 384;
    int k0 = (idx - m * 384) * 8;
    const float* src = (k0 < INDIM) ? (x + (size_t)m * INDIM + k0)
                                    : (hh + (size_t)m * HDIM + (k0 - INDIM));
    float4 lo = ((const float4*)src)[0];
    float4 hi = ((const float4*)src)[1];
    union { unsigned short us[8]; uint4 v; } o;
    o.us[0] = f2bf(lo.x); o.us[1] = f2bf(lo.y); o.us[2] = f2bf(lo.z); o.us[3] = f2bf(lo.w);
    o.us[4] = f2bf(hi.x); o.us[5] = f2bf(hi.y); o.us[6] = f2bf(hi.z); o.us[7] = f2bf(hi.w);
    *(uint4*)(A + (size_t)m * KDIM + k0) = o.v;
  } else {
    idx -= ACHUNKS;
    int np = idx / 384;
    int rem = idx - np * 384;
    int k0 = rem * 8;
    int j = np >> 2;
    int g = np & 3;
    int n = g * HDIM + j;
    const float* src = (k0 < INDIM) ? (w_ih + (size_t)n * INDIM + k0)
                                    : (w_hh + (size_t)n * HDIM + (k0 - INDIM));
    float4 lo = ((const float4*)src)[0];
    float4 hi = ((const float4*)src)[1];
    union { unsigned short us[8]; uint4 v; } o;
    o.us[0] = f2bf(lo.x); o.us[1] = f2bf(lo.y); o.us[2] = f2bf(lo.z); o.us[3] = f2bf(lo.w);
    o.us[4] = f2bf(hi.x); o.us[5] = f2bf(hi.y); o.us[6] = f2bf(hi.z); o.us[7] = f2bf(hi.w);
    *(uint4*)(W + (size_t)np * KDIM + k0) = o.v;
    if (rem == 0) bias[np] = b_ih[n] + b_hh[n];
  }
}

__device__ __forceinline__ void gload_lds16(const void* g, void* l) {
  __builtin_amdgcn_global_load_lds(
      (const __attribute__((address_space(1))) void*)g,
      (__attribute__((address_space(3))) void*)l, 16, 0, 0);
}

#define SB0 __builtin_amdgcn_sched_barrier(0)

// 256x256 tile, BK=32, 8 waves (2Mx4N), DOUBLE-buffered LDS (2 x 32KiB =
// 64KiB) -> 2 independent blocks/CU (cross-block stall/MFMA overlap, m114).
// Row-pair XOR swizzle (T2), setprio (T5), R4's 1-barrier-per-K-tile
// schedule; vmcnt(0) per tile is cheap (loads in flight a full body).
__global__ __launch_bounds__(512, 4) void lstm_gemm(
    const unsigned short* __restrict__ A,
    const unsigned short* __restrict__ W,
    const float* __restrict__ bias,
    const float* __restrict__ c,
    float* __restrict__ out) {
  extern __shared__ char smem[];  // 65536 bytes

  const int tid = threadIdx.x;
  const int lane = tid & 63;
  const int wid = tid >> 6;

  // XCD swizzle: xcd owns 2 tm slabs; tn sweeps slowest. Bijective over 512.
  const int bid = blockIdx.x;
  const int local = bid >> 3;
  const int tm = (bid & 7) * 2 + (local & 1);   // 0..15
  const int tn = local >> 1;                    // 0..31

  // ---- staging source decode (inverse swizzle, rule #21) ----
  int rowA0, clA0, rowA1, clA1;
  {
    int P0 = wid * 1024 + lane * 16;
    int P1 = 8192 + wid * 1024 + lane * 16;
    int r2, cp, cg;
    r2 = P0 >> 7; cp = (P0 >> 4) & 7; cg = cp ^ (r2 & 7);
    rowA0 = r2 * 2 + (cg >> 2); clA0 = cg & 3;
    r2 = P1 >> 7; cp = (P1 >> 4) & 7; cg = cp ^ (r2 & 7);
    rowA1 = r2 * 2 + (cg >> 2); clA1 = cg & 3;
  }
  const unsigned short* gA0 = A + (size_t)(tm * 256 + rowA0) * KDIM + clA0 * 8;
  const unsigned short* gA1 = A + (size_t)(tm * 256 + rowA1) * KDIM + clA1 * 8;
  const unsigned short* gB0 = W + (size_t)(tn * 256 + rowA0) * KDIM + clA0 * 8;
  const unsigned short* gB1 = W + (size_t)(tn * 256 + rowA1) * KDIM + clA1 * 8;
  const int ldA0 = wid * 1024;
  const int ldA1 = 8192 + wid * 1024;
  const int ldB0 = 16384 + wid * 1024;
  const int ldB1 = 24576 + wid * 1024;

  // ---- ds_read per-lane constants (swizzled) ----
  const int fr = lane & 15;
  const int fq = lane >> 4;
  const int wr = wid >> 2;    // 0..1 (rows)
  const int wc = wid & 3;     // 0..3 (cols)
  const int frh = fr >> 1;
  const int clA = (((fr & 1) << 2) | fq) ^ frh;
  const int aconst = wr * 8192 + frh * 128 + clA * 16;
  const int bconst = 16384 + wc * 4096 + frh * 128 + clA * 16;

  f32x4 acc[8][4] = {};
  short8 af[4], bf_[4], ag[4];

  // ---- prologue: stage tile 0 into buf0 ----
  gload_lds16(gA0, smem + ldA0);
  gload_lds16(gA1, smem + ldA1);
  gload_lds16(gB0, smem + ldB0);
  gload_lds16(gB1, smem + ldB1);
  gA0 += 32; gA1 += 32; gB0 += 32; gB1 += 32;
  asm volatile("s_waitcnt vmcnt(0)" ::: "memory");
  __builtin_amdgcn_s_barrier(); SB0;
  // issue af(0), bf_(0)
#pragma unroll
  for (int mi = 0; mi < 4; ++mi)
    af[mi] = *(const short8*)(smem + aconst + mi * 1024);
#pragma unroll
  for (int ni = 0; ni < 4; ++ni)
    bf_[ni] = *(const short8*)(smem + bconst + ni * 1024);

// Tile body. Entry: af(T),bf_(T) issued; buf[T%2] ready.
// Stage T+1 into buf[(T+1)%2]; vmcnt(0) before barrier (drain is cheap:
// loads were issued at body top; residual overlaps co-resident block).
#define TILE_BODY(T, STAGE_, PREF_)                                          \
  do {                                                                       \
    const char* rb = smem + ((T) & 1) * 32768;                               \
    char* nbuf = smem + (((T) + 1) & 1) * 32768;                             \
    if (STAGE_) {                                                            \
      gload_lds16(gA0, nbuf + ldA0);                                         \
      gload_lds16(gA1, nbuf + ldA1);                                         \
    }                                                                        \
    _Pragma("unroll")                                                        \
    for (int mi = 0; mi < 4; ++mi)                                           \
      ag[mi] = *(const short8*)(rb + aconst + (mi + 4) * 1024);              \
    SB0;                                                                     \
    __builtin_amdgcn_s_setprio(1);                                           \
    _Pragma("unroll")                                                        \
    for (int mi = 0; mi < 4; ++mi)                                           \
      _Pragma("unroll")                                                      \
      for (int ni = 0; ni < 4; ++ni)                                         \
        acc[mi][ni] = __builtin_amdgcn_mfma_f32_16x16x32_bf16(               \
            af[mi], bf_[ni], acc[mi][ni], 0, 0, 0);                          \
    __builtin_amdgcn_s_setprio(0);                                           \
    if (STAGE_) {                                                            \
      gload_lds16(gB0, nbuf + ldB0);                                         \
      gload_lds16(gB1, nbuf + ldB1);                                         \
      gA0 += 32; gA1 += 32; gB0 += 32; gB1 += 32;                            \
    }                                                                        \
    asm volatile("s_waitcnt vmcnt(0)" ::: "memory");                         \
    asm volatile("s_waitcnt lgkmcnt(0)" ::: "memory");                       \
    __builtin_amdgcn_s_barrier(); SB0;                                       \
    if (PREF_) {                                                             \
      _Pragma("unroll")                                                      \
      for (int mi = 0; mi < 4; ++mi)                                         \
        af[mi] = *(const short8*)(nbuf + aconst + mi * 1024);                \
    }                                                                        \
    SB0;                                                                     \
    __builtin_amdgcn_s_setprio(1);                                           \
    _Pragma("unroll")                                                        \
    for (int mi = 0; mi < 4; ++mi)                                           \
      _Pragma("unroll")                                                      \
      for (int ni = 0; ni < 4; ++ni)                                         \
        acc[mi + 4][ni] = __builtin_amdgcn_mfma_f32_16x16x32_bf16(           \
            ag[mi], bf_[ni], acc[mi + 4][ni], 0, 0, 0);                      \
    __builtin_amdgcn_s_setprio(0);                                           \
    if (PREF_) {                                                             \
      _Pragma("unroll")                                                      \
      for (int ni = 0; ni < 4; ++ni)                                         \
        bf_[ni] = *(const short8*)(nbuf + bconst + ni * 1024);               \
    }                                                                        \
  } while (0)

  for (int t = 0; t < NKT - 1; ++t) TILE_BODY(t, true, true);
  TILE_BODY(NKT - 1, false, false);
#undef TILE_BODY

  // ---- fused LSTM epilogue ----
  // Wave-private 4.5KiB LDS bounce (8 waves x 4608 B = 36864 <= 64KiB).
  // Safe: body-95's lgkm0+barrier retired every ds_read before ep writes.
  const int jw = fr;
  const int jg = tn * 64 + wc * 16 + jw;   // global j in [0,2048)
  const f32x4 bi = *(const f32x4*)(bias + tn * 256 + wc * 64 + jw * 4);
  float* ep = (float*)smem + wid * 1152;

#pragma unroll
  for (int mi = 0; mi < 8; ++mi) {
#pragma unroll
    for (int ni = 0; ni < 4; ++ni)
#pragma unroll
      for (int r = 0; r < 4; ++r)
        ep[(fq * 4 + r) * 68 + ni * 16 + fr] = acc[mi][ni][r];
    asm volatile("s_waitcnt lgkmcnt(0)" ::: "memory");
#pragma unroll
    for (int t4 = 0; t4 < 4; ++t4) {
      const int row = fq + t4 * 4;         // 0..15
      f32x4 g4 = *(const f32x4*)(ep + row * 68 + jw * 4);
      const float f_in = g4[0] + bi[0];
      const float i_in = g4[1] + bi[1];
      const float ic_in = g4[2] + bi[2];
      const float o_in = g4[3] + bi[3];
      const float ft = sigmoidf_(f_in);
      const float it = sigmoidf_(i_in);
      const float ics = __sinf(ic_in);
      const int mg = tm * 256 + wr * 128 + mi * 16 + row;
      const float cv = c[(size_t)mg * HDIM + jg];
      const float ct = cv * ft + ics * it;
      const float ot = sigmoidf_(o_in);
      const float ht = ot * __sinf(ct);
      out[(size_t)mg * HDIM + jg] = ht;
      out[OUT_HALF + (size_t)mg * HDIM + jg] = ct;
    }
    asm volatile("s_waitcnt lgkmcnt(0)" ::: "memory");
  }
}

extern "C" void kernel_launch(void* const* d_in, const int* in_sizes, int n_in,
                              void* d_out, int out_size, void* d_ws, size_t ws_size,
                              hipStream_t stream) {
  const float* x    = (const float*)d_in[0];
  const float* h    = (const float*)d_in[1];
  const float* c    = (const float*)d_in[2];
  const float* w_ih = (const float*)d_in[3];
  const float* w_hh = (const float*)d_in[4];
  const float* b_ih = (const float*)d_in[5];
  const float* b_hh = (const float*)d_in[6];
  float* out = (float*)d_out;

  char* ws = (char*)d_ws;
  unsigned short* Abf = (unsigned short*)ws;                       // 25,165,824 B
  unsigned short* Wbf = (unsigned short*)(ws + 25165824);          // 50,331,648 B
  float* bias = (float*)(ws + 25165824 + 50331648);                // 32,768 B

  hipFuncSetAttribute((const void*)lstm_gemm,
                      hipFuncAttributeMaxDynamicSharedMemorySize, 65536);

  pack_all<<<18432, 256, 0, stream>>>(x, h, w_ih, w_hh, b_ih, b_hh, Abf, Wbf, bias);
  lstm_gemm<<<512, 512, 65536, stream>>>(Abf, Wbf, bias, c, out);
}

// Round 13
// 318.932 us; speedup vs baseline: 5.8577x; 5.8577x over previous
//
#include <hip/hip_runtime.h>

typedef __attribute__((ext_vector_type(8))) short short8;
typedef __attribute__((ext_vector_type(4))) float f32x4;

// Problem dims
#define BDIM 4096
#define INDIM 1024
#define HDIM 2048
#define KDIM 3072   // IN + H
#define NDIM 8192   // 4*H
#define OUT_HALF 8388608  // 4096*2048
#define NKT 96      // K-tiles of 32
#define ACHUNKS 1572864

__device__ __forceinline__ unsigned short f2bf(float f) {
  unsigned u = __float_as_uint(f);
  u += 0x7FFFu + ((u >> 16) & 1u);
  return (unsigned short)(u >> 16);
}

__device__ __forceinline__ float sigmoidf_(float x) {
  return 1.0f / (1.0f + __expf(-x));
}

// Merged pack: A = [x|h] bf16 [4096][3072]; W' gate-interleaved bf16 [8192][3072];
// bias[n'] = b_ih + b_hh.
__global__ __launch_bounds__(256) void pack_all(
    const float* __restrict__ x, const float* __restrict__ hh,
    const float* __restrict__ w_ih, const float* __restrict__ w_hh,
    const float* __restrict__ b_ih, const float* __restrict__ b_hh,
    unsigned short* __restrict__ A, unsigned short* __restrict__ W,
    float* __restrict__ bias) {
  int idx = blockIdx.x * 256 + threadIdx.x;
  if (idx < ACHUNKS) {
    int m = idx / 384;
    int k0 = (idx - m * 384) * 8;
    const float* src = (k0 < INDIM) ? (x + (size_t)m * INDIM + k0)
                                    : (hh + (size_t)m * HDIM + (k0 - INDIM));
    float4 lo = ((const float4*)src)[0];
    float4 hi = ((const float4*)src)[1];
    union { unsigned short us[8]; uint4 v; } o;
    o.us[0] = f2bf(lo.x); o.us[1] = f2bf(lo.y); o.us[2] = f2bf(lo.z); o.us[3] = f2bf(lo.w);
    o.us[4] = f2bf(hi.x); o.us[5] = f2bf(hi.y); o.us[6] = f2bf(hi.z); o.us[7] = f2bf(hi.w);
    *(uint4*)(A + (size_t)m * KDIM + k0) = o.v;
  } else {
    idx -= ACHUNKS;
    int np = idx / 384;
    int rem = idx - np * 384;
    int k0 = rem * 8;
    int j = np >> 2;
    int g = np & 3;
    int n = g * HDIM + j;
    const float* src = (k0 < INDIM) ? (w_ih + (size_t)n * INDIM + k0)
                                    : (w_hh + (size_t)n * HDIM + (k0 - INDIM));
    float4 lo = ((const float4*)src)[0];
    float4 hi = ((const float4*)src)[1];
    union { unsigned short us[8]; uint4 v; } o;
    o.us[0] = f2bf(lo.x); o.us[1] = f2bf(lo.y); o.us[2] = f2bf(lo.z); o.us[3] = f2bf(lo.w);
    o.us[4] = f2bf(hi.x); o.us[5] = f2bf(hi.y); o.us[6] = f2bf(hi.z); o.us[7] = f2bf(hi.w);
    *(uint4*)(W + (size_t)np * KDIM + k0) = o.v;
    if (rem == 0) bias[np] = b_ih[n] + b_hh[n];
  }
}

__device__ __forceinline__ void gload_lds16(const void* g, void* l) {
  __builtin_amdgcn_global_load_lds(
      (const __attribute__((address_space(1))) void*)g,
      (__attribute__((address_space(3))) void*)l, 16, 0, 0);
}

#define SB0 __builtin_amdgcn_sched_barrier(0)

// 256x256 tile, BK=32, 8 waves (2Mx4N). A staged in 4-deep LDS ring
// (4 x 8KiB, row-pair XOR swizzle T2); B read straight from L2 into
// registers (global_load_dwordx4, bfA/bfB ping-pong, 1.5 bodies ahead) --
// halves LDS traffic and removes B from the barrier-synced critical path.
// R10's 1-barrier-per-K-tile rhythm, counted vmcnt (A-stage only), setprio.
__global__ __launch_bounds__(512, 2) void lstm_gemm(
    const unsigned short* __restrict__ A,
    const unsigned short* __restrict__ W,
    const float* __restrict__ bias,
    const float* __restrict__ c,
    float* __restrict__ out) {
  extern __shared__ char smem[];  // 36864 bytes (ring 32KiB; epilogue 36KiB)

  const int tid = threadIdx.x;
  const int lane = tid & 63;
  const int wid = tid >> 6;

  // XCD swizzle: xcd owns 2 tm slabs; tn sweeps slowest. Bijective over 512.
  const int bid = blockIdx.x;
  const int local = bid >> 3;
  const int tm = (bid & 7) * 2 + (local & 1);   // 0..15
  const int tn = local >> 1;                    // 0..31

  // ---- A staging source decode (inverse swizzle, rule #21) ----
  // A buf = 8KiB: 256 rows x 32 cols bf16, row-pair XOR swizzle.
  // Thread stages 16B at buf-local P = tid*16.
  const int r2s = tid >> 3;                 // row-pair 0..63 -> rows r2*2..
  const int cgs = (tid & 7) ^ (r2s & 7);    // logical chunk
  const int srowA = r2s * 2 + (cgs >> 2);   // 0..127?? r2s 0..63 -> rows 0..127
  // 512 threads x 16B = 8KiB covers rows 0..255: P = tid*16, r2 = P>>7 = tid>>3
  // gives row-pairs 0..63 = rows 0..127 only for tid<... NO: tid 0..511 ->
  // r2s 0..63? tid>>3 max = 63. But 256 rows = 128 row-pairs. Fix: P spans
  // 16384B? A buf is 256*32*2 = 16KiB. Ring 4x16KiB = 64KiB.
  const unsigned short* gA = A + (size_t)(tm * 256 + srowA) * KDIM + (cgs & 3) * 8;
  // second half (rows 128..255): P1 = 8192 + tid*16
  const int r2s1 = (8192 + tid * 16) >> 7;  // 64..127
  const int cgs1 = (tid & 7) ^ (r2s1 & 7);
  const int srowA1 = r2s1 * 2 + (cgs1 >> 2);
  const unsigned short* gA1 = A + (size_t)(tm * 256 + srowA1) * KDIM + (cgs1 & 3) * 8;
  const int ldA0 = tid * 16;
  const int ldA1 = 8192 + tid * 16;

  // ---- ds_read per-lane constants (swizzled; per-wave A 128x32 half) ----
  const int fr = lane & 15;
  const int fq = lane >> 4;
  const int wr = wid >> 2;    // 0..1 (M half)
  const int wc = wid & 3;     // 0..3 (N quarter)
  const int frh = fr >> 1;
  const int clA = (((fr & 1) << 2) | fq) ^ frh;
  const int aconst = wr * 8192 + frh * 128 + clA * 16;   // + mi*1024

  // ---- B global pointers (per-lane, frag-direct from L2) ----
  const unsigned short* gBf0 = W + (size_t)(tn * 256 + wc * 64 +  0 + fr) * KDIM + fq * 8;
  const unsigned short* gBf1 = W + (size_t)(tn * 256 + wc * 64 + 16 + fr) * KDIM + fq * 8;
  const unsigned short* gBf2 = W + (size_t)(tn * 256 + wc * 64 + 32 + fr) * KDIM + fq * 8;
  const unsigned short* gBf3 = W + (size_t)(tn * 256 + wc * 64 + 48 + fr) * KDIM + fq * 8;

  f32x4 acc[8][4] = {};
  short8 af[4], ag[4], bfA[4], bfB[4];

  // ---- prologue: stage A(0,1,2); load B(0)->bfA, B(1)->bfB ----
#pragma unroll
  for (int tt = 0; tt < 3; ++tt) {
    char* lb = smem + tt * 16384;
    gload_lds16(gA + (size_t)tt * 32, lb + ldA0);
    gload_lds16(gA1 + (size_t)tt * 32, lb + ldA1);
  }
  bfA[0] = *(const short8*)gBf0; bfA[1] = *(const short8*)gBf1;
  bfA[2] = *(const short8*)gBf2; bfA[3] = *(const short8*)gBf3;
  bfB[0] = *(const short8*)(gBf0 + 32); bfB[1] = *(const short8*)(gBf1 + 32);
  bfB[2] = *(const short8*)(gBf2 + 32); bfB[3] = *(const short8*)(gBf3 + 32);
  asm volatile("s_waitcnt vmcnt(8)" ::: "memory");   // A(0) landed
  __builtin_amdgcn_s_barrier(); SB0;
#pragma unroll
  for (int mi = 0; mi < 4; ++mi)
    af[mi] = *(const short8*)(smem + aconst + mi * 1024);

// Body T. Entry: af(T) issued, BFC=bf(T) in regs (or landing), BFN=bf(T+1)
// in flight; A(T+1),A(T+2) staged/landing.
// s1 stage A(T+3); ag(T) reads; MFMA-A; pre-barrier vmcnt(A(T+2) landed)+
// lgkm0; barrier; af(T+1) prefetch; MFMA-B; issue B(T+2)->BFC (freed).
#define TILE_BODY(T, VMSTR, STAGE_, PREFA_, PREFB_, BFC, BFN)                \
  do {                                                                       \
    const char* rb = smem + ((T) & 3) * 16384;                               \
    const char* rbn = smem + (((T) + 1) & 3) * 16384;                        \
    char* lb = smem + (((T) + 3) & 3) * 16384;                               \
    if (STAGE_) {                                                            \
      gload_lds16(gA + (size_t)((T) + 3) * 32, lb + ldA0);                   \
      gload_lds16(gA1 + (size_t)((T) + 3) * 32, lb + ldA1);                  \
    }                                                                        \
    _Pragma("unroll")                                                        \
    for (int mi = 0; mi < 4; ++mi)                                           \
      ag[mi] = *(const short8*)(rb + aconst + (mi + 4) * 1024);              \
    SB0;                                                                     \
    __builtin_amdgcn_s_setprio(1);                                           \
    _Pragma("unroll")                                                        \
    for (int mi = 0; mi < 4; ++mi)                                           \
      _Pragma("unroll")                                                      \
      for (int ni = 0; ni < 4; ++ni)                                         \
        acc[mi][ni] = __builtin_amdgcn_mfma_f32_16x16x32_bf16(               \
            af[mi], BFC[ni], acc[mi][ni], 0, 0, 0);                          \
    __builtin_amdgcn_s_setprio(0);                                           \
    SB0;                                                                     \
    asm volatile("s_waitcnt vmcnt(" VMSTR ")" ::: "memory");                 \
    asm volatile("s_waitcnt lgkmcnt(0)" ::: "memory");                       \
    __builtin_amdgcn_s_barrier(); SB0;                                       \
    if (PREFA_) {                                                            \
      _Pragma("unroll")                                                      \
      for (int mi = 0; mi < 4; ++mi)                                         \
        af[mi] = *(const short8*)(rbn + aconst + mi * 1024);                 \
    }                                                                        \
    SB0;                                                                     \
    __builtin_amdgcn_s_setprio(1);                                           \
    _Pragma("unroll")                                                        \
    for (int mi = 0; mi < 4; ++mi)                                           \
      _Pragma("unroll")                                                      \
      for (int ni = 0; ni < 4; ++ni)                                         \
        acc[mi + 4][ni] = __builtin_amdgcn_mfma_f32_16x16x32_bf16(           \
            ag[mi], BFC[ni], acc[mi + 4][ni], 0, 0, 0);                      \
    __builtin_amdgcn_s_setprio(0);                                           \
    SB0;                                                                     \
    if (PREFB_) {                                                            \
      BFC[0] = *(const short8*)(gBf0 + (size_t)((T) + 2) * 32);              \
      BFC[1] = *(const short8*)(gBf1 + (size_t)((T) + 2) * 32);              \
      BFC[2] = *(const short8*)(gBf2 + (size_t)((T) + 2) * 32);              \
      BFC[3] = *(const short8*)(gBf3 + (size_t)((T) + 2) * 32);              \
    }                                                                        \
    SB0;                                                                     \
  } while (0)

  for (int t = 0; t < 92; t += 2) {
    TILE_BODY(t,     "6", true, true, true, bfA, bfB);
    TILE_BODY(t + 1, "6", true, true, true, bfB, bfA);
  }
  TILE_BODY(92, "6", true,  true,  true,  bfA, bfB);
  TILE_BODY(93, "0", false, true,  true,  bfB, bfA);
  TILE_BODY(94, "0", false, true,  false, bfA, bfB);
  TILE_BODY(95, "0", false, false, false, bfB, bfA);
#undef TILE_BODY

  // ---- fused LSTM epilogue ----
  // Wave-private LDS bounce, stride 68 floats (8 x 4608 = 36864 B). Safe:
  // last body's lgkm0+barrier retired all ds_reads before ep writes.
  const int jw = fr;
  const int jg = tn * 64 + wc * 16 + jw;   // global j in [0,2048)
  const f32x4 bi = *(const f32x4*)(bias + tn * 256 + wc * 64 + jw * 4);
  float* ep = (float*)smem + wid * 1152;

#pragma unroll
  for (int mi = 0; mi < 8; ++mi) {
#pragma unroll
    for (int ni = 0; ni < 4; ++ni)
#pragma unroll
      for (int r = 0; r < 4; ++r)
        ep[(fq * 4 + r) * 68 + ni * 16 + fr] = acc[mi][ni][r];
    asm volatile("s_waitcnt lgkmcnt(0)" ::: "memory");
#pragma unroll
    for (int t4 = 0; t4 < 4; ++t4) {
      const int row = fq + t4 * 4;         // 0..15
      f32x4 g4 = *(const f32x4*)(ep + row * 68 + jw * 4);
      const float f_in = g4[0] + bi[0];
      const float i_in = g4[1] + bi[1];
      const float ic_in = g4[2] + bi[2];
      const float o_in = g4[3] + bi[3];
      const float ft = sigmoidf_(f_in);
      const float it = sigmoidf_(i_in);
      const float ics = __sinf(ic_in);
      const int mg = tm * 256 + wr * 128 + mi * 16 + row;
      const float cv = c[(size_t)mg * HDIM + jg];
      const float ct = cv * ft + ics * it;
      const float ot = sigmoidf_(o_in);
      const float ht = ot * __sinf(ct);
      out[(size_t)mg * HDIM + jg] = ht;
      out[OUT_HALF + (size_t)mg * HDIM + jg] = ct;
    }
    asm volatile("s_waitcnt lgkmcnt(0)" ::: "memory");
  }
}

extern "C" void kernel_launch(void* const* d_in, const int* in_sizes, int n_in,
                              void* d_out, int out_size, void* d_ws, size_t ws_size,
                              hipStream_t stream) {
  const float* x    = (const float*)d_in[0];
  const float* h    = (const float*)d_in[1];
  const float* c    = (const float*)d_in[2];
  const float* w_ih = (const float*)d_in[3];
  const float* w_hh = (const float*)d_in[4];
  const float* b_ih = (const float*)d_in[5];
  const float* b_hh = (const float*)d_in[6];
  float* out = (float*)d_out;

  char* ws = (char*)d_ws;
  unsigned short* Abf = (unsigned short*)ws;                       // 25,165,824 B
  unsigned short* Wbf = (unsigned short*)(ws + 25165824);          // 50,331,648 B
  float* bias = (float*)(ws + 25165824 + 50331648);                // 32,768 B

  hipFuncSetAttribute((const void*)lstm_gemm,
                      hipFuncAttributeMaxDynamicSharedMemorySize, 65536);

  pack_all<<<18432, 256, 0, stream>>>(x, h, w_ih, w_hh, b_ih, b_hh, Abf, Wbf, bias);
  lstm_gemm<<<512, 512, 65536, stream>>>(Abf, Wbf, bias, c, out);
}

// Round 14
// 219.489 us; speedup vs baseline: 8.5117x; 1.4531x over previous
//
#include <hip/hip_runtime.h>

typedef __attribute__((ext_vector_type(8))) short short8;
typedef __attribute__((ext_vector_type(4))) float f32x4;

// Problem dims
#define BDIM 4096
#define INDIM 1024
#define HDIM 2048
#define KDIM 3072   // IN + H
#define NDIM 8192   // 4*H
#define OUT_HALF 8388608  // 4096*2048
#define NKT 96      // K-tiles of 32
#define ACHUNKS 1572864

__device__ __forceinline__ unsigned short f2bf(float f) {
  unsigned u = __float_as_uint(f);
  u += 0x7FFFu + ((u >> 16) & 1u);
  return (unsigned short)(u >> 16);
}

__device__ __forceinline__ float sigmoidf_(float x) {
  return 1.0f / (1.0f + __expf(-x));
}

// Merged pack: A = [x|h] bf16 [4096][3072]; W' gate-interleaved bf16 [8192][3072];
// bias[n'] = b_ih + b_hh.
__global__ __launch_bounds__(256) void pack_all(
    const float* __restrict__ x, const float* __restrict__ hh,
    const float* __restrict__ w_ih, const float* __restrict__ w_hh,
    const float* __restrict__ b_ih, const float* __restrict__ b_hh,
    unsigned short* __restrict__ A, unsigned short* __restrict__ W,
    float* __restrict__ bias) {
  int idx = blockIdx.x * 256 + threadIdx.x;
  if (idx < ACHUNKS) {
    int m = idx / 384;
    int k0 = (idx - m * 384) * 8;
    const float* src = (k0 < INDIM) ? (x + (size_t)m * INDIM + k0)
                                    : (hh + (size_t)m * HDIM + (k0 - INDIM));
    float4 lo = ((const float4*)src)[0];
    float4 hi = ((const float4*)src)[1];
    union { unsigned short us[8]; uint4 v; } o;
    o.us[0] = f2bf(lo.x); o.us[1] = f2bf(lo.y); o.us[2] = f2bf(lo.z); o.us[3] = f2bf(lo.w);
    o.us[4] = f2bf(hi.x); o.us[5] = f2bf(hi.y); o.us[6] = f2bf(hi.z); o.us[7] = f2bf(hi.w);
    *(uint4*)(A + (size_t)m * KDIM + k0) = o.v;
  } else {
    idx -= ACHUNKS;
    int np = idx / 384;
    int rem = idx - np * 384;
    int k0 = rem * 8;
    int j = np >> 2;
    int g = np & 3;
    int n = g * HDIM + j;
    const float* src = (k0 < INDIM) ? (w_ih + (size_t)n * INDIM + k0)
                                    : (w_hh + (size_t)n * HDIM + (k0 - INDIM));
    float4 lo = ((const float4*)src)[0];
    float4 hi = ((const float4*)src)[1];
    union { unsigned short us[8]; uint4 v; } o;
    o.us[0] = f2bf(lo.x); o.us[1] = f2bf(lo.y); o.us[2] = f2bf(lo.z); o.us[3] = f2bf(lo.w);
    o.us[4] = f2bf(hi.x); o.us[5] = f2bf(hi.y); o.us[6] = f2bf(hi.z); o.us[7] = f2bf(hi.w);
    *(uint4*)(W + (size_t)np * KDIM + k0) = o.v;
    if (rem == 0) bias[np] = b_ih[n] + b_hh[n];
  }
}

__device__ __forceinline__ void gload_lds16(const void* g, void* l) {
  __builtin_amdgcn_global_load_lds(
      (const __attribute__((address_space(1))) void*)g,
      (__attribute__((address_space(3))) void*)l, 16, 0, 0);
}

#define SB0 __builtin_amdgcn_sched_barrier(0)

// R10-exact GEMM (best measured): 256x256 tile, BK=32, 8 waves (2Mx4N),
// 4-deep LDS ring (4 x 32KiB), row-pair XOR swizzle (T2), counted vmcnt (T4),
// setprio (T5), 1-barrier-per-K-tile pipelined schedule (af prefetch alone
// post-barrier, bf_ prefetch after MFMA-B), mfma_f32_16x16x32_bf16.
__global__ __launch_bounds__(512, 2) void lstm_gemm(
    const unsigned short* __restrict__ A,
    const unsigned short* __restrict__ W,
    const float* __restrict__ bias,
    const float* __restrict__ c,
    float* __restrict__ out) {
  extern __shared__ char smem[];  // 131072 bytes

  const int tid = threadIdx.x;
  const int lane = tid & 63;
  const int wid = tid >> 6;

  // XCD swizzle: xcd owns 2 tm slabs; tn sweeps slowest. Bijective over 512.
  const int bid = blockIdx.x;
  const int local = bid >> 3;
  const int tm = (bid & 7) * 2 + (local & 1);   // 0..15
  const int tn = local >> 1;                    // 0..31

  // ---- staging source decode (inverse swizzle, rule #21) ----
  int rowA0, clA0, rowA1, clA1;
  {
    int P0 = wid * 1024 + lane * 16;
    int P1 = 8192 + wid * 1024 + lane * 16;
    int r2, cp, cg;
    r2 = P0 >> 7; cp = (P0 >> 4) & 7; cg = cp ^ (r2 & 7);
    rowA0 = r2 * 2 + (cg >> 2); clA0 = cg & 3;
    r2 = P1 >> 7; cp = (P1 >> 4) & 7; cg = cp ^ (r2 & 7);
    rowA1 = r2 * 2 + (cg >> 2); clA1 = cg & 3;
  }
  const unsigned short* gA0 = A + (size_t)(tm * 256 + rowA0) * KDIM + clA0 * 8;
  const unsigned short* gA1 = A + (size_t)(tm * 256 + rowA1) * KDIM + clA1 * 8;
  const unsigned short* gB0 = W + (size_t)(tn * 256 + rowA0) * KDIM + clA0 * 8;
  const unsigned short* gB1 = W + (size_t)(tn * 256 + rowA1) * KDIM + clA1 * 8;
  const int ldA0 = wid * 1024;
  const int ldA1 = 8192 + wid * 1024;
  const int ldB0 = 16384 + wid * 1024;
  const int ldB1 = 24576 + wid * 1024;

  // ---- ds_read per-lane constants (swizzled) ----
  const int fr = lane & 15;
  const int fq = lane >> 4;
  const int wr = wid >> 2;    // 0..1 (rows)
  const int wc = wid & 3;     // 0..3 (cols)
  const int frh = fr >> 1;
  const int clA = (((fr & 1) << 2) | fq) ^ frh;
  const int aconst = wr * 8192 + frh * 128 + clA * 16;
  const int bconst = 16384 + wc * 4096 + frh * 128 + clA * 16;

  f32x4 acc[8][4] = {};
  short8 af[4], bf_[4], ag[4];

  // ---- prologue: stage tiles 0,1,2 ----
#pragma unroll
  for (int tt = 0; tt < 3; ++tt) {
    char* lb = smem + tt * 32768;
    gload_lds16(gA0, lb + ldA0);
    gload_lds16(gA1, lb + ldA1);
    gload_lds16(gB0, lb + ldB0);
    gload_lds16(gB1, lb + ldB1);
    gA0 += 32; gA1 += 32; gB0 += 32; gB1 += 32;
  }
  asm volatile("s_waitcnt vmcnt(8)" ::: "memory");   // tile 0 landed
  __builtin_amdgcn_s_barrier(); SB0;
  // issue af(0), bf_(0)
#pragma unroll
  for (int mi = 0; mi < 4; ++mi)
    af[mi] = *(const short8*)(smem + aconst + mi * 1024);
#pragma unroll
  for (int ni = 0; ni < 4; ++ni)
    bf_[ni] = *(const short8*)(smem + bconst + ni * 1024);

// Tile body. Entry: af(T),bf_(T) issued; vm queue = stages for T+1,T+2 (8).
#define TILE_BODY(T, VMSTR, STAGE_, PREF_)                                   \
  do {                                                                       \
    const char* rb = smem + ((T) & 3) * 32768;                               \
    const char* rbn = smem + (((T) + 1) & 3) * 32768;                        \
    char* lb = smem + (((T) + 3) & 3) * 32768;                               \
    if (STAGE_) {                                                            \
      gload_lds16(gA0, lb + ldA0);                                           \
      gload_lds16(gA1, lb + ldA1);                                           \
    }                                                                        \
    _Pragma("unroll")                                                        \
    for (int mi = 0; mi < 4; ++mi)                                           \
      ag[mi] = *(const short8*)(rb + aconst + (mi + 4) * 1024);              \
    SB0;                                                                     \
    __builtin_amdgcn_s_setprio(1);                                           \
    _Pragma("unroll")                                                        \
    for (int mi = 0; mi < 4; ++mi)                                           \
      _Pragma("unroll")                                                      \
      for (int ni = 0; ni < 4; ++ni)                                         \
        acc[mi][ni] = __builtin_amdgcn_mfma_f32_16x16x32_bf16(               \
            af[mi], bf_[ni], acc[mi][ni], 0, 0, 0);                          \
    __builtin_amdgcn_s_setprio(0);                                           \
    if (STAGE_) {                                                            \
      gload_lds16(gB0, lb + ldB0);                                           \
      gload_lds16(gB1, lb + ldB1);                                           \
      gA0 += 32; gA1 += 32; gB0 += 32; gB1 += 32;                            \
    }                                                                        \
    asm volatile("s_waitcnt vmcnt(" VMSTR ")" ::: "memory");                 \
    asm volatile("s_waitcnt lgkmcnt(0)" ::: "memory");                       \
    __builtin_amdgcn_s_barrier(); SB0;                                       \
    if (PREF_) {                                                             \
      _Pragma("unroll")                                                      \
      for (int mi = 0; mi < 4; ++mi)                                         \
        af[mi] = *(const short8*)(rbn + aconst + mi * 1024);                 \
    }                                                                        \
    SB0;                                                                     \
    __builtin_amdgcn_s_setprio(1);                                           \
    _Pragma("unroll")                                                        \
    for (int mi = 0; mi < 4; ++mi)                                           \
      _Pragma("unroll")                                                      \
      for (int ni = 0; ni < 4; ++ni)                                         \
        acc[mi + 4][ni] = __builtin_amdgcn_mfma_f32_16x16x32_bf16(           \
            ag[mi], bf_[ni], acc[mi + 4][ni], 0, 0, 0);                      \
    __builtin_amdgcn_s_setprio(0);                                           \
    if (PREF_) {                                                             \
      _Pragma("unroll")                                                      \
      for (int ni = 0; ni < 4; ++ni)                                         \
        bf_[ni] = *(const short8*)(rbn + bconst + ni * 1024);                \
    }                                                                        \
  } while (0)

  for (int t = 0; t < NKT - 3; ++t) TILE_BODY(t, "8", true, true);
  TILE_BODY(NKT - 3, "4", false, true);
  TILE_BODY(NKT - 2, "0", false, true);
  TILE_BODY(NKT - 1, "0", false, false);
#undef TILE_BODY

  // ---- fused LSTM epilogue ----
  // Wave-private 4.5KiB LDS bounce (stride 68 floats; bufs 0-1 region, final
  // K-tile read buf 3 -> untouched; waves only touch their own region).
  const int jw = fr;
  const int jg = tn * 64 + wc * 16 + jw;   // global j in [0,2048)
  const f32x4 bi = *(const f32x4*)(bias + tn * 256 + wc * 64 + jw * 4);
  float* ep = (float*)smem + wid * 1152;

#pragma unroll
  for (int mi = 0; mi < 8; ++mi) {
#pragma unroll
    for (int ni = 0; ni < 4; ++ni)
#pragma unroll
      for (int r = 0; r < 4; ++r)
        ep[(fq * 4 + r) * 68 + ni * 16 + fr] = acc[mi][ni][r];
    asm volatile("s_waitcnt lgkmcnt(0)" ::: "memory");
#pragma unroll
    for (int t4 = 0; t4 < 4; ++t4) {
      const int row = fq + t4 * 4;         // 0..15
      f32x4 g4 = *(const f32x4*)(ep + row * 68 + jw * 4);
      const float f_in = g4[0] + bi[0];
      const float i_in = g4[1] + bi[1];
      const float ic_in = g4[2] + bi[2];
      const float o_in = g4[3] + bi[3];
      const float ft = sigmoidf_(f_in);
      const float it = sigmoidf_(i_in);
      const float ics = __sinf(ic_in);
      const int mg = tm * 256 + wr * 128 + mi * 16 + row;
      const float cv = c[(size_t)mg * HDIM + jg];
      const float ct = cv * ft + ics * it;
      const float ot = sigmoidf_(o_in);
      const float ht = ot * __sinf(ct);
      out[(size_t)mg * HDIM + jg] = ht;
      out[OUT_HALF + (size_t)mg * HDIM + jg] = ct;
    }
    asm volatile("s_waitcnt lgkmcnt(0)" ::: "memory");
  }
}

extern "C" void kernel_launch(void* const* d_in, const int* in_sizes, int n_in,
                              void* d_out, int out_size, void* d_ws, size_t ws_size,
                              hipStream_t stream) {
  const float* x    = (const float*)d_in[0];
  const float* h    = (const float*)d_in[1];
  const float* c    = (const float*)d_in[2];
  const float* w_ih = (const float*)d_in[3];
  const float* w_hh = (const float*)d_in[4];
  const float* b_ih = (const float*)d_in[5];
  const float* b_hh = (const float*)d_in[6];
  float* out = (float*)d_out;

  char* ws = (char*)d_ws;
  unsigned short* Abf = (unsigned short*)ws;                       // 25,165,824 B
  unsigned short* Wbf = (unsigned short*)(ws + 25165824);          // 50,331,648 B
  float* bias = (float*)(ws + 25165824 + 50331648);                // 32,768 B

  hipFuncSetAttribute((const void*)lstm_gemm,
                      hipFuncAttributeMaxDynamicSharedMemorySize, 131072);

  pack_all<<<18432, 256, 0, stream>>>(x, h, w_ih, w_hh, b_ih, b_hh, Abf, Wbf, bias);
  lstm_gemm<<<512, 512, 131072, stream>>>(Abf, Wbf, bias, c, out);
}